// Round 6
// baseline (221.769 us; speedup 1.0000x reference)
//
#include <hip/hip_runtime.h>

typedef __attribute__((ext_vector_type(8))) short bf16x8;
typedef __attribute__((ext_vector_type(4))) short bf16x4;
typedef __attribute__((ext_vector_type(4))) float f32x4;
typedef unsigned int u32;
typedef unsigned short u16;
typedef unsigned long long u64;

#define NSEQ 4096
#define DD   64
#define NEG  3.0e4f
// log2(10000)/32 : inv_freq[i] = 2^(-i * L32)
#define L32  0.4152410118609203f

__device__ __forceinline__ u16 f2bf(float f) {
    union { float f; u32 i; } x; x.f = f;
    u32 r = x.i + 0x7fffu + ((x.i >> 16) & 1u);   // RNE, finite inputs only
    return (u16)(r >> 16);
}

// Stage 128 RoPE'd K rows (keys gkbase..gkbase+127) into Kb (bf16). 512
// threads: thread = (row r = tid>>2, dim-quarter qt = tid&3, 16 dims each).
// Invalid rows -> zeros (finite; masked later). K is fp32.
__device__ __forceinline__ void stage_k(int tid, int bh, int gkbase,
                                        const float* __restrict__ K,
                                        u16 (*Kb)[72])
{
    const int r = tid >> 2, qt = tid & 3, e0 = qt * 16;
    const int gk = gkbase + r;
    u16 y[16] __attribute__((aligned(16)));
    if (gk >= 0) {
        const float* kp = K + (size_t)(bh * NSEQ + gk) * DD;
        float a[16], b[16];
        #pragma unroll
        for (int i = 0; i < 4; ++i) {
            *(float4*)&a[i * 4] = *(const float4*)(kp + e0 + i * 4);
            *(float4*)&b[i * 4] = *(const float4*)(kp + (e0 ^ 32) + i * 4);  // rotate_half partners
        }
        const float gkf = (float)gk;
        const float sgn = (e0 < 32) ? -1.f : 1.f;      // uniform per qt
        const int i0 = e0 & 31;                        // freq index base
        #pragma unroll
        for (int jj = 0; jj < 16; ++jj) {
            float ang = gkf * exp2f(-(float)(i0 + jj) * L32);
            float cc = cosf(ang), ss = sinf(ang);
            y[jj] = f2bf(a[jj] * cc + sgn * b[jj] * ss);
        }
    } else {
        #pragma unroll
        for (int jj = 0; jj < 16; ++jj) y[jj] = 0;
    }
    *(uint4*)&Kb[r][e0]     = ((const uint4*)y)[0];
    *(uint4*)&Kb[r][e0 + 8] = ((const uint4*)y)[1];
}

// one block = one (b*h, window): 128 queries x 256 keys, 8 waves x 16 queries.
// fp32 global I/O; bf16 only inside (MFMA operands). S^T = K*Q^T so softmax
// reduces with 2 shuffles; K staged in two 128-key passes (LDS < 64 KB); P
// goes through a wave-private LDS scratch (per-wave DS ordering, no barrier).
__global__ __launch_bounds__(512) void lattn(
    const float* __restrict__ Q, const float* __restrict__ K,
    const float* __restrict__ V, const int* __restrict__ M,
    float* __restrict__ O)
{
    __shared__ u16 Kb[128][72];      // 18,432 B  RoPE'd keys (one 128-key pass)
    __shared__ u16 Vt[64][264];      // 33,792 B  V^T [dim][key 0..255]
    __shared__ u16 Ps[8][16][40];    // 10,240 B  per-wave P chunk [query][key%32]
                                     // total 62,464 B < 64 KiB

    const int w = blockIdx.x, bh = blockIdx.y, batch = bh >> 2;  // H = 4
    const int tid = threadIdx.x, lane = tid & 63, wv = tid >> 6;
    const int kbase = w * 128 - 128;
    const int m_ = lane & 15, qd = lane >> 4;
    const int rb = wv * 16;
    const int tq = w * 128 + rb + m_;          // this lane's query position

    // validity bits for 256 keys (pad & bin-mask), registers only
    u64 vb[4];
    #pragma unroll
    for (int i = 0; i < 4; ++i) {
        int gk = kbase + i * 64 + lane;
        int mv = (gk >= 0) ? M[batch * NSEQ + gk] : 0;
        vb[i] = __ballot(mv != 0);
    }

    // ---- stage V^T (once): thread = (key j = tid>>1, dim-half h = tid&1) ----
    {
        const int j = tid >> 1, h = tid & 1, gk = kbase + j;
        float rv[32];
        if (gk >= 0) {
            const float* vr = V + (size_t)(bh * NSEQ + gk) * DD + h * 32;
            #pragma unroll
            for (int i = 0; i < 8; ++i) *(float4*)&rv[i * 4] = *(const float4*)(vr + i * 4);
        } else {
            #pragma unroll
            for (int i = 0; i < 32; ++i) rv[i] = 0.f;  // finite; P==0 there
        }
        #pragma unroll
        for (int i = 0; i < 32; ++i) Vt[h * 32 + i][j] = f2bf(rv[i]);
    }

    // ---- stage K pass 0 (keys kbase..kbase+127) ----
    stage_k(tid, bh, kbase, K, Kb);

    // ---- Q fragments from global (fp32), RoPE in registers ----
    // B-frag: lane holds Q[n=lane&15][k=qd*8+j]; RoPE pairs (e, e+32) are the
    // two k-half fragments.
    bf16x8 qf0, qf1;
    {
        const float* qr = Q + (size_t)(bh * NSEQ + tq) * DD;
        float lo[8], hi[8];
        *(float4*)&lo[0] = *(const float4*)(qr + qd * 8);
        *(float4*)&lo[4] = *(const float4*)(qr + qd * 8 + 4);
        *(float4*)&hi[0] = *(const float4*)(qr + qd * 8 + 32);
        *(float4*)&hi[4] = *(const float4*)(qr + qd * 8 + 36);
        const float tf = (float)tq;
        #pragma unroll
        for (int jj = 0; jj < 8; ++jj) {
            float ang = tf * exp2f(-(float)(qd * 8 + jj) * L32);
            float cc = cosf(ang), ss = sinf(ang);
            qf0[jj] = (short)f2bf(lo[jj] * cc - hi[jj] * ss);
            qf1[jj] = (short)f2bf(hi[jj] * cc + lo[jj] * ss);
        }
    }

    __syncthreads();

    // ---- S^T = K·Q^T, pass 0: key-tiles t=0..7 ----
    f32x4 acc[16];
    const f32x4 zf = {0.f, 0.f, 0.f, 0.f};
    #pragma unroll
    for (int t = 0; t < 8; ++t) {
        bf16x8 kf0 = *(const bf16x8*)&Kb[t * 16 + m_][qd * 8];
        bf16x8 kf1 = *(const bf16x8*)&Kb[t * 16 + m_][32 + qd * 8];
        f32x4 c0 = __builtin_amdgcn_mfma_f32_16x16x32_bf16(kf0, qf0, zf, 0, 0, 0);
        acc[t]   = __builtin_amdgcn_mfma_f32_16x16x32_bf16(kf1, qf1, c0, 0, 0, 0);
    }

    __syncthreads();                                   // all waves done with pass 0

    // ---- stage K pass 1 (keys kbase+128..kbase+255) ----
    stage_k(tid, bh, kbase + 128, K, Kb);

    __syncthreads();

    // ---- S^T pass 1: key-tiles t=8..15 ----
    #pragma unroll
    for (int t = 8; t < 16; ++t) {
        bf16x8 kf0 = *(const bf16x8*)&Kb[(t - 8) * 16 + m_][qd * 8];
        bf16x8 kf1 = *(const bf16x8*)&Kb[(t - 8) * 16 + m_][32 + qd * 8];
        f32x4 c0 = __builtin_amdgcn_mfma_f32_16x16x32_bf16(kf0, qf0, zf, 0, 0, 0);
        acc[t]   = __builtin_amdgcn_mfma_f32_16x16x32_bf16(kf1, qf1, c0, 0, 0, 0);
    }

    // ---- mask + softmax. C/D: lane holds key nn=t*16+qd*4+r, query col m_ ----
    const int lim = tq - kbase;                        // causal: nn <= lim
    float mx = -NEG;
    #pragma unroll
    for (int t = 0; t < 16; ++t)
        #pragma unroll
        for (int r = 0; r < 4; ++r) {
            int nn = t * 16 + qd * 4 + r;
            bool ok = (nn <= lim) && ((vb[t >> 2] >> (nn & 63)) & 1ull);
            float s = ok ? acc[t][r] * 0.125f : -NEG;  // scale = d^-0.5
            acc[t][r] = s;
            mx = fmaxf(mx, s);
        }
    mx = fmaxf(mx, __shfl_xor(mx, 16));
    mx = fmaxf(mx, __shfl_xor(mx, 32));
    float sum = 0.f;
    #pragma unroll
    for (int t = 0; t < 16; ++t)
        #pragma unroll
        for (int r = 0; r < 4; ++r) {
            float p = __expf(acc[t][r] - mx);          // <= 0 argument
            acc[t][r] = p; sum += p;
        }
    sum += __shfl_xor(sum, 16);
    sum += __shfl_xor(sum, 32);
    const float is = 1.f / sum;                        // sum >= 1 (self key valid)

    // ---- O = P·V, per 32-key chunk; P via wave-private LDS scratch ----
    // Wave-private region => no inter-wave hazard; per-wave DS ops complete
    // in order, so write->read needs no barrier (sched_barrier pins order).
    f32x4 o[4] = {zf, zf, zf, zf};
    #pragma unroll
    for (int kc = 0; kc < 8; ++kc) {
        bf16x4 w0, w1;
        #pragma unroll
        for (int r = 0; r < 4; ++r) {
            w0[r] = (short)f2bf(acc[2 * kc][r] * is);      // keys kc*32+4qd+r
            w1[r] = (short)f2bf(acc[2 * kc + 1][r] * is);  // keys kc*32+16+4qd+r
        }
        *(bf16x4*)&Ps[wv][m_][qd * 4]      = w0;
        *(bf16x4*)&Ps[wv][m_][16 + qd * 4] = w1;
        __builtin_amdgcn_sched_barrier(0);             // keep read after writes
        bf16x8 pf = *(const bf16x8*)&Ps[wv][m_][qd * 8];
        __builtin_amdgcn_sched_barrier(0);             // keep next writes after read
        #pragma unroll
        for (int et = 0; et < 4; ++et) {
            bf16x8 vf = *(const bf16x8*)&Vt[et * 16 + m_][kc * 32 + qd * 8];
            o[et] = __builtin_amdgcn_mfma_f32_16x16x32_bf16(pf, vf, o[et], 0, 0, 0);
        }
    }

    // C layout: lane holds out[query = rb + qd*4 + r][e = et*16 + m_]; fp32 out
    float* ob = O + (size_t)(bh * NSEQ + w * 128 + rb + qd * 4) * DD;
    #pragma unroll
    for (int r = 0; r < 4; ++r)
        #pragma unroll
        for (int et = 0; et < 4; ++et)
            ob[r * DD + et * 16 + m_] = o[et][r];
}

extern "C" void kernel_launch(void* const* d_in, const int* in_sizes, int n_in,
                              void* d_out, int out_size, void* d_ws, size_t ws_size,
                              hipStream_t stream) {
    const float* q = (const float*)d_in[0];
    const float* k = (const float*)d_in[1];
    const float* v = (const float*)d_in[2];
    const int*   m = (const int*)d_in[3];
    float* o = (float*)d_out;
    dim3 grid(32, 32);   // x = window, y = b*h
    lattn<<<grid, 512, 0, stream>>>(q, k, v, m, o);
}

// Round 7
// 153.481 us; speedup vs baseline: 1.4449x; 1.4449x over previous
//
#include <hip/hip_runtime.h>

typedef __attribute__((ext_vector_type(8))) short bf16x8;
typedef __attribute__((ext_vector_type(4))) short bf16x4;
typedef __attribute__((ext_vector_type(4))) float f32x4;
typedef unsigned int u32;
typedef unsigned short u16;
typedef unsigned long long u64;

#define NSEQ 4096
#define DD   64
#define NEG  3.0e4f
// log2(10000)/32 : inv_freq[i] = 2^(-i * L32)
#define L32  0.4152410118609203f

__device__ __forceinline__ u16 f2bf(float f) {
    union { float f; u32 i; } x; x.f = f;
    u32 r = x.i + 0x7fffu + ((x.i >> 16) & 1u);   // RNE, finite inputs only
    return (u16)(r >> 16);
}

// Stage 128 RoPE'd K rows (keys gkbase..gkbase+127) into Kb (bf16).
// cos/sin via split-angle tables: t*theta_i = (hi*64+lo)*theta_i, complex mult.
// thread = (row r = tid>>2, dim-quarter qt = tid&3, 16 dims each).
__device__ __forceinline__ void stage_k(int tid, int bh, int gkbase, int hibase,
                                        const float* __restrict__ K,
                                        u16 (*Kb)[72],
                                        const float2 (*tabLo)[64],
                                        const float2 (*tabHi)[32])
{
    const int r = tid >> 2, qt = tid & 3, e0 = qt * 16;
    const int gk = gkbase + r;
    u16 y[16] __attribute__((aligned(16)));
    if (gk >= 0) {
        const float* kp = K + (size_t)(bh * NSEQ + gk) * DD;
        float a[16], b[16];
        #pragma unroll
        for (int i = 0; i < 4; ++i) {
            *(float4*)&a[i * 4] = *(const float4*)(kp + e0 + i * 4);
            *(float4*)&b[i * 4] = *(const float4*)(kp + (e0 ^ 32) + i * 4);  // rotate_half partners
        }
        const int lo = gk & 63, h = (gk >> 6) - hibase;   // h in [0,4)
        const float sgn = (e0 < 32) ? -1.f : 1.f;          // uniform per qt
        const int i0 = e0 & 31;                            // freq index base
        #pragma unroll
        for (int jj = 0; jj < 16; ++jj) {
            float2 L = tabLo[i0 + jj][lo];
            float2 H = tabHi[h][i0 + jj];
            float cc = H.x * L.x - H.y * L.y;              // cos(hi+lo)
            float ss = H.y * L.x + H.x * L.y;              // sin(hi+lo)
            y[jj] = f2bf(a[jj] * cc + sgn * b[jj] * ss);
        }
    } else {
        #pragma unroll
        for (int jj = 0; jj < 16; ++jj) y[jj] = 0;
    }
    *(uint4*)&Kb[r][e0]     = ((const uint4*)y)[0];
    *(uint4*)&Kb[r][e0 + 8] = ((const uint4*)y)[1];
}

// one block = one (b*h, window): 128 queries x 256 keys, 8 waves x 16 queries.
// fp32 global I/O; bf16 only for MFMA operands. S^T = K*Q^T (softmax = 2
// shuffles); K staged in two 128-key passes; P via wave-private LDS scratch.
__global__ __launch_bounds__(512) void lattn(
    const float* __restrict__ Q, const float* __restrict__ K,
    const float* __restrict__ V, const int* __restrict__ M,
    float* __restrict__ O)
{
    __shared__ u16 Kb[128][72];              // 18,432 B
    __shared__ u16 Vt[64][264];              // 33,792 B  V^T [dim][key 0..255]
    __shared__ u16 Ps[8][16][40];            // 10,240 B  per-wave P scratch
    __shared__ __align__(16) float2 tabLo[32][64];  // 16,384 B  (cos,sin)(lo*theta_i)
    __shared__ float2 tabHi[4][32];          //  1,024 B  (cos,sin)(hi64*theta_i)
                                             // total 79,872 B -> 2 blocks/CU

    const int w = blockIdx.x, bh = blockIdx.y, batch = bh >> 2;  // H = 4
    const int tid = threadIdx.x, lane = tid & 63, wv = tid >> 6;
    const int kbase = w * 128 - 128;
    const int hibase = (kbase > 0 ? kbase : 0) >> 6;
    const int m_ = lane & 15, qd = lane >> 4;
    const int rb = wv * 16;
    const int tq = w * 128 + rb + m_;          // this lane's query position

    // ---- build cos/sin tables: 2048 lo-entries (4/thread) + 128 hi-entries ----
    {
        const int e = tid * 4, fi = e >> 6, lo = e & 63;
        const float th = exp2f(-(float)fi * L32);
        float2 t4[4];
        #pragma unroll
        for (int s = 0; s < 4; ++s) {
            float sv, cv;
            sincosf((float)(lo + s) * th, &sv, &cv);
            t4[s] = make_float2(cv, sv);
        }
        *(float4*)&tabLo[fi][lo]     = *(float4*)&t4[0];
        *(float4*)&tabLo[fi][lo + 2] = *(float4*)&t4[2];
        if (tid < 128) {
            const int h = tid >> 5, f2 = tid & 31;
            const float th2 = exp2f(-(float)f2 * L32);
            float sv, cv;
            sincosf((float)((hibase + h) * 64) * th2, &sv, &cv);
            tabHi[h][f2] = make_float2(cv, sv);
        }
    }

    // validity bits for 256 keys (pad & bin-mask), registers only
    u64 vb[4];
    #pragma unroll
    for (int i = 0; i < 4; ++i) {
        int gk = kbase + i * 64 + lane;
        int mv = (gk >= 0) ? M[batch * NSEQ + gk] : 0;
        vb[i] = __ballot(mv != 0);
    }

    // ---- stage V^T (no table dep): thread = (key j = tid>>1, half h = tid&1) ----
    {
        const int j = tid >> 1, h = tid & 1, gk = kbase + j;
        float rv[32];
        if (gk >= 0) {
            const float* vr = V + (size_t)(bh * NSEQ + gk) * DD + h * 32;
            #pragma unroll
            for (int i = 0; i < 8; ++i) *(float4*)&rv[i * 4] = *(const float4*)(vr + i * 4);
        } else {
            #pragma unroll
            for (int i = 0; i < 32; ++i) rv[i] = 0.f;  // finite; P==0 there
        }
        #pragma unroll
        for (int i = 0; i < 32; ++i) Vt[h * 32 + i][j] = f2bf(rv[i]);
    }

    __syncthreads();                                   // tables ready

    // ---- stage K pass 0 (keys kbase..kbase+127) ----
    stage_k(tid, bh, kbase, hibase, K, Kb, tabLo, tabHi);

    // ---- Q fragments from global (fp32), RoPE via tables ----
    // B-frag: lane holds Q[n=lane&15][k=qd*8+j]; RoPE pairs (e, e+32) are the
    // two k-half fragments.
    bf16x8 qf0, qf1;
    {
        const float* qr = Q + (size_t)(bh * NSEQ + tq) * DD;
        float ql[8], qh_[8];
        *(float4*)&ql[0]  = *(const float4*)(qr + qd * 8);
        *(float4*)&ql[4]  = *(const float4*)(qr + qd * 8 + 4);
        *(float4*)&qh_[0] = *(const float4*)(qr + qd * 8 + 32);
        *(float4*)&qh_[4] = *(const float4*)(qr + qd * 8 + 36);
        const int qlo = tq & 63, qh = (tq >> 6) - hibase;   // qh in [0,4)
        #pragma unroll
        for (int jj = 0; jj < 8; ++jj) {
            const int fi = qd * 8 + jj;                     // freq index < 32
            float2 L = tabLo[fi][qlo];
            float2 H = tabHi[qh][fi];
            float cc = H.x * L.x - H.y * L.y;
            float ss = H.y * L.x + H.x * L.y;
            qf0[jj] = (short)f2bf(ql[jj]  * cc - qh_[jj] * ss);
            qf1[jj] = (short)f2bf(qh_[jj] * cc + ql[jj]  * ss);
        }
    }

    __syncthreads();                                   // Kb pass 0 ready

    // ---- S^T = K·Q^T, pass 0: key-tiles t=0..7 ----
    f32x4 acc[16];
    const f32x4 zf = {0.f, 0.f, 0.f, 0.f};
    #pragma unroll
    for (int t = 0; t < 8; ++t) {
        bf16x8 kf0 = *(const bf16x8*)&Kb[t * 16 + m_][qd * 8];
        bf16x8 kf1 = *(const bf16x8*)&Kb[t * 16 + m_][32 + qd * 8];
        f32x4 c0 = __builtin_amdgcn_mfma_f32_16x16x32_bf16(kf0, qf0, zf, 0, 0, 0);
        acc[t]   = __builtin_amdgcn_mfma_f32_16x16x32_bf16(kf1, qf1, c0, 0, 0, 0);
    }

    __syncthreads();                                   // all waves done with pass 0

    // ---- stage K pass 1 (keys kbase+128..kbase+255) ----
    stage_k(tid, bh, kbase + 128, hibase, K, Kb, tabLo, tabHi);

    __syncthreads();

    // ---- S^T pass 1: key-tiles t=8..15 ----
    #pragma unroll
    for (int t = 8; t < 16; ++t) {
        bf16x8 kf0 = *(const bf16x8*)&Kb[(t - 8) * 16 + m_][qd * 8];
        bf16x8 kf1 = *(const bf16x8*)&Kb[(t - 8) * 16 + m_][32 + qd * 8];
        f32x4 c0 = __builtin_amdgcn_mfma_f32_16x16x32_bf16(kf0, qf0, zf, 0, 0, 0);
        acc[t]   = __builtin_amdgcn_mfma_f32_16x16x32_bf16(kf1, qf1, c0, 0, 0, 0);
    }

    // ---- mask + softmax. C/D: lane holds key nn=t*16+qd*4+r, query col m_ ----
    const int lim = tq - kbase;                        // causal: nn <= lim
    float mx = -NEG;
    #pragma unroll
    for (int t = 0; t < 16; ++t)
        #pragma unroll
        for (int r = 0; r < 4; ++r) {
            int nn = t * 16 + qd * 4 + r;
            bool ok = (nn <= lim) && ((vb[t >> 2] >> (nn & 63)) & 1ull);
            float s = ok ? acc[t][r] * 0.125f : -NEG;  // scale = d^-0.5
            acc[t][r] = s;
            mx = fmaxf(mx, s);
        }
    mx = fmaxf(mx, __shfl_xor(mx, 16));
    mx = fmaxf(mx, __shfl_xor(mx, 32));
    float sum = 0.f;
    #pragma unroll
    for (int t = 0; t < 16; ++t)
        #pragma unroll
        for (int r = 0; r < 4; ++r) {
            float p = __expf(acc[t][r] - mx);          // <= 0 argument
            acc[t][r] = p; sum += p;
        }
    sum += __shfl_xor(sum, 16);
    sum += __shfl_xor(sum, 32);
    const float is = 1.f / sum;                        // sum >= 1 (self key valid)

    // ---- O = P·V, per 32-key chunk; P via wave-private LDS scratch ----
    // Wave-private region => no inter-wave hazard; per-wave DS ops complete
    // in order (sched_barrier pins the write->read order).
    f32x4 o[4] = {zf, zf, zf, zf};
    #pragma unroll
    for (int kc = 0; kc < 8; ++kc) {
        bf16x4 w0, w1;
        #pragma unroll
        for (int r = 0; r < 4; ++r) {
            w0[r] = (short)f2bf(acc[2 * kc][r] * is);      // keys kc*32+4qd+r
            w1[r] = (short)f2bf(acc[2 * kc + 1][r] * is);  // keys kc*32+16+4qd+r
        }
        *(bf16x4*)&Ps[wv][m_][qd * 4]      = w0;
        *(bf16x4*)&Ps[wv][m_][16 + qd * 4] = w1;
        __builtin_amdgcn_sched_barrier(0);             // keep read after writes
        bf16x8 pf = *(const bf16x8*)&Ps[wv][m_][qd * 8];
        __builtin_amdgcn_sched_barrier(0);             // keep next writes after read
        #pragma unroll
        for (int et = 0; et < 4; ++et) {
            bf16x8 vf = *(const bf16x8*)&Vt[et * 16 + m_][kc * 32 + qd * 8];
            o[et] = __builtin_amdgcn_mfma_f32_16x16x32_bf16(pf, vf, o[et], 0, 0, 0);
        }
    }

    // C layout: lane holds out[query = rb + qd*4 + r][e = et*16 + m_]; fp32 out
    float* ob = O + (size_t)(bh * NSEQ + w * 128 + rb + qd * 4) * DD;
    #pragma unroll
    for (int r = 0; r < 4; ++r)
        #pragma unroll
        for (int et = 0; et < 4; ++et)
            ob[r * DD + et * 16 + m_] = o[et][r];
}

extern "C" void kernel_launch(void* const* d_in, const int* in_sizes, int n_in,
                              void* d_out, int out_size, void* d_ws, size_t ws_size,
                              hipStream_t stream) {
    const float* q = (const float*)d_in[0];
    const float* k = (const float*)d_in[1];
    const float* v = (const float*)d_in[2];
    const int*   m = (const int*)d_in[3];
    float* o = (float*)d_out;
    dim3 grid(32, 32);   // x = window, y = b*h
    lattn<<<grid, 512, 0, stream>>>(q, k, v, m, o);
}